// Round 1
// baseline (50.900 us; speedup 1.0000x reference)
//
#include <hip/hip_runtime.h>
#include <math.h>

#define GREEDY_EPS 1e-6f

// One block per row. 1024 threads stride over V/4 float4s.
// argmax with first-index tie-breaking (matches jnp.argmax).
__global__ __launch_bounds__(1024) void sampler_kernel(
    const float* __restrict__ logits,
    const float* __restrict__ temps,
    const float* __restrict__ u,
    int* __restrict__ out,
    int V)
{
    const int row = blockIdx.x;
    const int tid = threadIdx.x;
    const float t = temps[row];
    const bool greedy = (t <= GREEDY_EPS);

    const float4* __restrict__ lg4 =
        (const float4*)(logits + (size_t)row * (size_t)V);
    const float4* __restrict__ uu4 =
        (const float4*)(u + (size_t)row * (size_t)V);
    const int nvec = V >> 2;  // V = 128000, divisible by 4

    float bestVal = -INFINITY;
    int bestIdx = 0;

    if (greedy) {
        // temp <= eps: argmax(logits) only; skip reading u entirely.
        for (int i = tid; i < nvec; i += blockDim.x) {
            float4 l = lg4[i];
            int base = i << 2;
            if (l.x > bestVal) { bestVal = l.x; bestIdx = base; }
            if (l.y > bestVal) { bestVal = l.y; bestIdx = base + 1; }
            if (l.z > bestVal) { bestVal = l.z; bestIdx = base + 2; }
            if (l.w > bestVal) { bestVal = l.w; bestIdx = base + 3; }
        }
    } else {
        // argmax(logits / t - log(-log(u))) — precise div + precise logf
        // to track the numpy reference's rounding.
        for (int i = tid; i < nvec; i += blockDim.x) {
            float4 l = lg4[i];
            float4 g = uu4[i];
            int base = i << 2;
            float v0 = l.x / t - logf(-logf(g.x));
            float v1 = l.y / t - logf(-logf(g.y));
            float v2 = l.z / t - logf(-logf(g.z));
            float v3 = l.w / t - logf(-logf(g.w));
            if (v0 > bestVal) { bestVal = v0; bestIdx = base; }
            if (v1 > bestVal) { bestVal = v1; bestIdx = base + 1; }
            if (v2 > bestVal) { bestVal = v2; bestIdx = base + 2; }
            if (v3 > bestVal) { bestVal = v3; bestIdx = base + 3; }
        }
    }

    // Wave (64-lane) reduction, tie-break prefers lower index.
    const int lane = tid & 63;
    const int wave = tid >> 6;
    #pragma unroll
    for (int off = 32; off > 0; off >>= 1) {
        float ov = __shfl_down(bestVal, off);
        int   oi = __shfl_down(bestIdx, off);
        if (ov > bestVal || (ov == bestVal && oi < bestIdx)) {
            bestVal = ov; bestIdx = oi;
        }
    }

    __shared__ float sVal[16];
    __shared__ int   sIdx[16];
    if (lane == 0) { sVal[wave] = bestVal; sIdx[wave] = bestIdx; }
    __syncthreads();

    if (tid == 0) {
        float bv = sVal[0]; int bi = sIdx[0];
        const int nw = (int)(blockDim.x >> 6);
        for (int w = 1; w < nw; ++w) {
            float v = sVal[w]; int ix = sIdx[w];
            if (v > bv || (v == bv && ix < bi)) { bv = v; bi = ix; }
        }
        out[row] = bi;
    }
}

extern "C" void kernel_launch(void* const* d_in, const int* in_sizes, int n_in,
                              void* d_out, int out_size, void* d_ws, size_t ws_size,
                              hipStream_t stream) {
    const float* logits = (const float*)d_in[0];
    const float* temps  = (const float*)d_in[1];
    const float* u      = (const float*)d_in[2];
    int* out = (int*)d_out;

    const int B = in_sizes[1];            // 256
    const int V = in_sizes[0] / B;        // 128000

    sampler_kernel<<<dim3(B), dim3(1024), 0, stream>>>(logits, temps, u, out, V);
}

// Round 2
// 47.015 us; speedup vs baseline: 1.0826x; 1.0826x over previous
//
#include <hip/hip_runtime.h>
#include <math.h>

#define GREEDY_EPS 1e-6f
#define SEG 2          // segments per row
#define BLK 1024       // threads per block

// Monotone float->uint key: a > b  <=>  fkey(a) > fkey(b)  (no NaNs in data)
__device__ inline unsigned int fkey(float v) {
    unsigned int b = __float_as_uint(v);
    return (b & 0x80000000u) ? ~b : (b | 0x80000000u);
}

// Phase 1: each block computes argmax over one contiguous segment of a row,
// writes packed (valueKey, ~idx) u64 to ws. Written unconditionally every
// call -> no ws init needed, deterministic.
__global__ __launch_bounds__(BLK) void sampler_partial(
    const float* __restrict__ logits,
    const float* __restrict__ temps,
    const float* __restrict__ u,
    unsigned long long* __restrict__ ws,
    int V)
{
    const int row = blockIdx.x >> 1;      // SEG == 2
    const int seg = blockIdx.x & 1;
    const int tid = threadIdx.x;

    const int segLen = V / SEG;           // 64000, divisible by 4
    const int segOff = seg * segLen;
    const int nvec   = segLen >> 2;       // 16000 float4s

    const float t = temps[row];
    const bool greedy = (t <= GREEDY_EPS);

    const float4* __restrict__ lg4 =
        (const float4*)(logits + (size_t)row * (size_t)V + segOff);
    const float4* __restrict__ uu4 =
        (const float4*)(u + (size_t)row * (size_t)V + segOff);

    float bestVal = -INFINITY;
    int bestIdx = 0;

    if (greedy) {
        for (int i = tid; i < nvec; i += BLK) {
            float4 l = lg4[i];
            int base = i << 2;
            if (l.x > bestVal) { bestVal = l.x; bestIdx = base; }
            if (l.y > bestVal) { bestVal = l.y; bestIdx = base + 1; }
            if (l.z > bestVal) { bestVal = l.z; bestIdx = base + 2; }
            if (l.w > bestVal) { bestVal = l.w; bestIdx = base + 3; }
        }
    } else {
        // argmax(l/t + g) == argmax(l + t*g), t > 0.
        // g = -log(-log u) = -ln2 * (log2(-log2 u) + log2(ln2))
        // value = l + a*G + a*c1, a = -t*ln2, G = log2(-log2 u), c1 = log2(ln2)
        const float a   = -t * 0.69314718055994530942f;
        const float ac1 = a * -0.52876637294489770425f;
        for (int i = tid; i < nvec; i += BLK) {
            float4 l = lg4[i];
            float4 g = uu4[i];
            int base = i << 2;
            float G0 = __log2f(-__log2f(g.x));
            float G1 = __log2f(-__log2f(g.y));
            float G2 = __log2f(-__log2f(g.z));
            float G3 = __log2f(-__log2f(g.w));
            float v0 = fmaf(a, G0, l.x + ac1);
            float v1 = fmaf(a, G1, l.y + ac1);
            float v2 = fmaf(a, G2, l.z + ac1);
            float v3 = fmaf(a, G3, l.w + ac1);
            if (v0 > bestVal) { bestVal = v0; bestIdx = base; }
            if (v1 > bestVal) { bestVal = v1; bestIdx = base + 1; }
            if (v2 > bestVal) { bestVal = v2; bestIdx = base + 2; }
            if (v3 > bestVal) { bestVal = v3; bestIdx = base + 3; }
        }
    }

    // Wave reduction, tie-break prefers lower index.
    const int lane = tid & 63;
    const int wave = tid >> 6;
    #pragma unroll
    for (int off = 32; off > 0; off >>= 1) {
        float ov = __shfl_down(bestVal, off);
        int   oi = __shfl_down(bestIdx, off);
        if (ov > bestVal || (ov == bestVal && oi < bestIdx)) {
            bestVal = ov; bestIdx = oi;
        }
    }

    __shared__ float sVal[BLK / 64];
    __shared__ int   sIdx[BLK / 64];
    if (lane == 0) { sVal[wave] = bestVal; sIdx[wave] = bestIdx; }
    __syncthreads();

    if (tid == 0) {
        float bv = sVal[0]; int bi = sIdx[0];
        #pragma unroll
        for (int w = 1; w < BLK / 64; ++w) {
            float v = sVal[w]; int ix = sIdx[w];
            if (v > bv || (v == bv && ix < bi)) { bv = v; bi = ix; }
        }
        int gidx = bi + segOff;
        unsigned long long packed =
            ((unsigned long long)fkey(bv) << 32) |
            (unsigned long long)(0xFFFFFFFFu - (unsigned int)gidx);
        ws[(size_t)row * SEG + seg] = packed;
    }
}

// Phase 2: reduce SEG partials per row, decode index.
__global__ void sampler_final(const unsigned long long* __restrict__ ws,
                              int* __restrict__ out, int B)
{
    int row = blockIdx.x * blockDim.x + threadIdx.x;
    if (row < B) {
        unsigned long long m = ws[(size_t)row * SEG];
        #pragma unroll
        for (int s = 1; s < SEG; ++s) {
            unsigned long long v = ws[(size_t)row * SEG + s];
            if (v > m) m = v;
        }
        out[row] = (int)(0xFFFFFFFFu - (unsigned int)(m & 0xFFFFFFFFu));
    }
}

extern "C" void kernel_launch(void* const* d_in, const int* in_sizes, int n_in,
                              void* d_out, int out_size, void* d_ws, size_t ws_size,
                              hipStream_t stream) {
    const float* logits = (const float*)d_in[0];
    const float* temps  = (const float*)d_in[1];
    const float* u      = (const float*)d_in[2];
    int* out = (int*)d_out;

    const int B = in_sizes[1];            // 256
    const int V = in_sizes[0] / B;        // 128000

    unsigned long long* ws = (unsigned long long*)d_ws;

    sampler_partial<<<dim3(B * SEG), dim3(BLK), 0, stream>>>(
        logits, temps, u, ws, V);
    sampler_final<<<dim3((B + 255) / 256), dim3(256), 0, stream>>>(ws, out, B);
}

// Round 3
// 45.869 us; speedup vs baseline: 1.1097x; 1.0250x over previous
//
#include <hip/hip_runtime.h>
#include <math.h>

#define GREEDY_EPS 1e-6f
#define SEG 4          // segments per row
#define BLK 1024       // threads per block

typedef float f32x4 __attribute__((ext_vector_type(4)));

// Monotone float->uint key: a > b  <=>  fkey(a) > fkey(b)  (no NaNs in data)
__device__ inline unsigned int fkey(float v) {
    unsigned int b = __float_as_uint(v);
    return (b & 0x80000000u) ? ~b : (b | 0x80000000u);
}

// Phase 1: each block computes argmax over one contiguous segment of a row,
// writes packed (valueKey, ~idx) u64 to ws. Written unconditionally every
// call -> no ws init needed, deterministic.
//
// logits: normal (cacheable) loads -> 131 MB fits in 256 MB L3, stays
//         resident across replays.
// u:      non-temporal loads -> streams from HBM without evicting logits.
__global__ __launch_bounds__(BLK) void sampler_partial(
    const float* __restrict__ logits,
    const float* __restrict__ temps,
    const float* __restrict__ u,
    unsigned long long* __restrict__ ws,
    int V)
{
    const int row = blockIdx.x >> 2;      // SEG == 4
    const int seg = blockIdx.x & 3;
    const int tid = threadIdx.x;

    const int segLen = V / SEG;           // 32000, divisible by 4
    const int segOff = seg * segLen;
    const int nvec   = segLen >> 2;       // 8000 float4s

    const float t = temps[row];
    const bool greedy = (t <= GREEDY_EPS);

    const f32x4* __restrict__ lg4 =
        (const f32x4*)(logits + (size_t)row * (size_t)V + segOff);
    const f32x4* __restrict__ uu4 =
        (const f32x4*)(u + (size_t)row * (size_t)V + segOff);

    float bestVal = -INFINITY;
    int bestIdx = 0;

    if (greedy) {
        for (int i = tid; i < nvec; i += BLK) {
            f32x4 l = lg4[i];
            int base = i << 2;
            if (l.x > bestVal) { bestVal = l.x; bestIdx = base; }
            if (l.y > bestVal) { bestVal = l.y; bestIdx = base + 1; }
            if (l.z > bestVal) { bestVal = l.z; bestIdx = base + 2; }
            if (l.w > bestVal) { bestVal = l.w; bestIdx = base + 3; }
        }
    } else {
        // argmax(l/t + g) == argmax(l + t*g), t > 0.
        // g = -log(-log u) = -ln2 * (log2(-log2 u) + log2(ln2))
        // value = l + a*G + a*c1, a = -t*ln2, G = log2(-log2 u), c1 = log2(ln2)
        const float a   = -t * 0.69314718055994530942f;
        const float ac1 = a * -0.52876637294489770425f;
        for (int i = tid; i < nvec; i += BLK) {
            f32x4 l = lg4[i];
            f32x4 g = __builtin_nontemporal_load(&uu4[i]);
            int base = i << 2;
            float G0 = __log2f(-__log2f(g.x));
            float G1 = __log2f(-__log2f(g.y));
            float G2 = __log2f(-__log2f(g.z));
            float G3 = __log2f(-__log2f(g.w));
            float v0 = fmaf(a, G0, l.x + ac1);
            float v1 = fmaf(a, G1, l.y + ac1);
            float v2 = fmaf(a, G2, l.z + ac1);
            float v3 = fmaf(a, G3, l.w + ac1);
            if (v0 > bestVal) { bestVal = v0; bestIdx = base; }
            if (v1 > bestVal) { bestVal = v1; bestIdx = base + 1; }
            if (v2 > bestVal) { bestVal = v2; bestIdx = base + 2; }
            if (v3 > bestVal) { bestVal = v3; bestIdx = base + 3; }
        }
    }

    // Wave reduction, tie-break prefers lower index.
    const int lane = tid & 63;
    const int wave = tid >> 6;
    #pragma unroll
    for (int off = 32; off > 0; off >>= 1) {
        float ov = __shfl_down(bestVal, off);
        int   oi = __shfl_down(bestIdx, off);
        if (ov > bestVal || (ov == bestVal && oi < bestIdx)) {
            bestVal = ov; bestIdx = oi;
        }
    }

    __shared__ float sVal[BLK / 64];
    __shared__ int   sIdx[BLK / 64];
    if (lane == 0) { sVal[wave] = bestVal; sIdx[wave] = bestIdx; }
    __syncthreads();

    if (tid == 0) {
        float bv = sVal[0]; int bi = sIdx[0];
        #pragma unroll
        for (int w = 1; w < BLK / 64; ++w) {
            float v = sVal[w]; int ix = sIdx[w];
            if (v > bv || (v == bv && ix < bi)) { bv = v; bi = ix; }
        }
        int gidx = bi + segOff;
        unsigned long long packed =
            ((unsigned long long)fkey(bv) << 32) |
            (unsigned long long)(0xFFFFFFFFu - (unsigned int)gidx);
        ws[(size_t)row * SEG + seg] = packed;
    }
}

// Phase 2: reduce SEG partials per row, decode index.
__global__ void sampler_final(const unsigned long long* __restrict__ ws,
                              int* __restrict__ out, int B)
{
    int row = blockIdx.x * blockDim.x + threadIdx.x;
    if (row < B) {
        unsigned long long m = ws[(size_t)row * SEG];
        #pragma unroll
        for (int s = 1; s < SEG; ++s) {
            unsigned long long v = ws[(size_t)row * SEG + s];
            if (v > m) m = v;
        }
        out[row] = (int)(0xFFFFFFFFu - (unsigned int)(m & 0xFFFFFFFFu));
    }
}

extern "C" void kernel_launch(void* const* d_in, const int* in_sizes, int n_in,
                              void* d_out, int out_size, void* d_ws, size_t ws_size,
                              hipStream_t stream) {
    const float* logits = (const float*)d_in[0];
    const float* temps  = (const float*)d_in[1];
    const float* u      = (const float*)d_in[2];
    int* out = (int*)d_out;

    const int B = in_sizes[1];            // 256
    const int V = in_sizes[0] / B;        // 128000

    unsigned long long* ws = (unsigned long long*)d_ws;

    sampler_partial<<<dim3(B * SEG), dim3(BLK), 0, stream>>>(
        logits, temps, u, ws, V);
    sampler_final<<<dim3((B + 255) / 256), dim3(256), 0, stream>>>(ws, out, B);
}